// Round 7
// baseline (75.567 us; speedup 1.0000x reference)
//
#include <hip/hip_runtime.h>

#define HH 128
#define WW 128
#define HWSZ (HH*WW)
#define NB 4
#define KK 9
#define XSTR 96   // NHWC channel stride in bf16 elems (192 B): c0-63 input, c64 mask, c65-95 zero

typedef short bf16x8 __attribute__((ext_vector_type(8)));
typedef float f32x4 __attribute__((ext_vector_type(4)));

union U4 { uint4 v; unsigned a[4]; };

__device__ __forceinline__ short f2bf(float f) {
    union { float f; unsigned u; } v; v.f = f;
    unsigned r = v.u + 0x7FFFu + ((v.u >> 16) & 1u);
    return (short)(r >> 16);
}
__device__ __forceinline__ float bflo(unsigned dw) {
    union { unsigned u; float f; } v; v.u = dw << 16; return v.f;
}
__device__ __forceinline__ float bfhi(unsigned dw) {
    union { unsigned u; float f; } v; v.u = dw & 0xFFFF0000u; return v.f;
}
__device__ __forceinline__ unsigned cvtpk(float lo, float hi) {
    unsigned r;
    asm("v_cvt_pk_bf16_f32 %0, %1, %2" : "=v"(r) : "v"(lo), "v"(hi));
    return r;
}

// ---------------- prep: NHWC-bf16 transpose (banded) + weight repack ----------------
// xt : [NB*HWSZ][96] bf16: c0-63 input, c64 = mask_in, c65-95 = 0
// wd2: deform B frags [ks(2)][tap(9)][nt(4)][lane(64)][8] bf16 (36,864)
// wc2: conv   B frags [ks(3)][tap(9)][nt(2)][lane(64)][8] bf16 (27,648); ks=2 = mask channel
__global__ __launch_bounds__(256) void prep_kernel(
    const float* __restrict__ input,
    const float* __restrict__ mask_in,
    const float* __restrict__ weight,
    const float* __restrict__ offset_w,
    const float* __restrict__ mask_w,
    short* __restrict__ xt,
    short* __restrict__ wd2,
    short* __restrict__ wc2)
{
    __shared__ short lds[64 * 104];   // stride 104 shorts = 208 B -> 16B-aligned rows
    int bid = blockIdx.x;
    if (bid < 1024) {
        int wg = ((bid & 7) << 7) | (bid >> 3);   // XCD band swizzle
        int g0 = wg * 64;
        int b  = g0 >> 14;
        int p0 = g0 & (HWSZ - 1);
        int px = threadIdx.x & 63;
        int cq = threadIdx.x >> 6;
#pragma unroll
        for (int it = 0; it < 24; ++it) {
            int c = it * 4 + cq;
            float v;
            if (c < 64)       v = input[((size_t)(b * 64 + c)) * HWSZ + p0 + px];
            else if (c == 64) v = mask_in[(size_t)b * HWSZ + p0 + px];
            else              v = 0.f;
            lds[px * 104 + c] = f2bf(v);
        }
        __syncthreads();
#pragma unroll
        for (int it = 0; it < 3; ++it) {
            int idx = it * 256 + threadIdx.x;
            if (idx < 768) {
                int ppx = idx / 12, s = idx - ppx * 12;
                bf16x8 v = *(const bf16x8*)&lds[ppx * 104 + s * 8];
                *(bf16x8*)&xt[((size_t)(g0 + ppx)) * XSTR + s * 8] = v;
            }
        }
    } else {
        int idx = (bid - 1024) * 256 + threadIdx.x;   // 0..36863
        if (idx < 36864) {
            int j = idx & 7, l = (idx >> 3) & 63, f = idx >> 9;
            int nt = f & 3, t9 = f >> 2;
            int k = t9 % 9, ks = t9 / 9;
            int o = nt * 16 + (l & 15);
            int c = ks * 32 + ((l >> 4) & 3) * 8 + j;
            wd2[idx] = f2bf(weight[(o * 64 + c) * 9 + k]);
        }
        if (idx < 27648) {
            int j = idx & 7, l = (idx >> 3) & 63, f = idx >> 9;
            int nt = f & 1, t9 = f >> 1;
            int k = t9 % 9, ks = t9 / 9;
            int o = nt * 16 + (l & 15);
            int c = ks * 32 + ((l >> 4) & 3) * 8 + j;
            float v = 0.f;
            if (c <= 64) {
                if (o < 18)      v = offset_w[(o * 65 + c) * 9 + k];
                else if (o < 27) v = mask_w[((o - 18) * 65 + c) * 9 + k];
            }
            wc2[idx] = f2bf(v);
        }
    }
}

// ---------------- conv (65ch in, 27ch out, 3x3, pad 1): MFMA, 3 K-phases, B from global ----------------
// off_px: [NB*HWSZ][32] f32: 0..17 offsets (dy/dx), 18..26 sigmoid(mask)
__global__ __launch_bounds__(256, 4) void conv_offset_mfma(
    const short* __restrict__ xt, const bf16x8* __restrict__ wc,
    const float* __restrict__ offset_b, const float* __restrict__ mask_b,
    float* __restrict__ off_px)
{
    int bid = blockIdx.x;
    int wg = ((bid & 7) << 7) | (bid >> 3);
    int wid = threadIdx.x >> 6, lane = threadIdx.x & 63;
    int r = lane & 15, lg = lane >> 4;
    int g0 = wg * 64 + wid * 16;
    int gp = g0 + r;
    int b = gp >> 14, p = gp & (HWSZ - 1);
    int i = p >> 7, j = p & 127;
    const short* xb = xt + ((size_t)(b << 14)) * XSTR;

    int  nbv[9];
    bool vv[9];
#pragma unroll
    for (int t = 0; t < 9; ++t) {
        int yy = i + t / 3 - 1, xx = j + t % 3 - 1;
        bool v = ((unsigned)yy < HH) && ((unsigned)xx < WW);
        vv[t] = v;
        nbv[t] = (v ? yy * WW + xx : 0) * XSTR;
    }

    f32x4 acc0 = {0,0,0,0}, acc1 = {0,0,0,0};

#pragma unroll
    for (int ks = 0; ks < 3; ++ks) {
        int co = ks * 32 + lg * 8;
#pragma unroll
        for (int t = 0; t < 9; ++t) {
            union { bf16x8 s8; uint4 u; } A;
            A.u = *(const uint4*)(xb + nbv[t] + co);
            if (!vv[t]) { A.u.x = 0; A.u.y = 0; A.u.z = 0; A.u.w = 0; }
            const bf16x8* wck = wc + ((ks * 9 + t) * 2) * 64 + lane;
            bf16x8 B0 = wck[0];
            bf16x8 B1 = wck[64];
            acc0 = __builtin_amdgcn_mfma_f32_16x16x32_bf16(A.s8, B0, acc0, 0, 0, 0);
            acc1 = __builtin_amdgcn_mfma_f32_16x16x32_bf16(A.s8, B1, acc1, 0, 0, 0);
        }
    }

    int oc = lane & 15, pr0 = lg * 4;
#pragma unroll
    for (int rr = 0; rr < 4; ++rr) {
        int gpix = g0 + pr0 + rr;
        float* orow = off_px + (size_t)gpix * 32;
        orow[oc] = acc0[rr] + offset_b[oc];
        int oc2 = 16 + oc;
        if (oc2 < 18) {
            orow[oc2] = acc1[rr] + offset_b[oc2];
        } else if (oc2 < 27) {
            float z = acc1[rr] + mask_b[oc2 - 18];
            orow[oc2] = 1.f / (1.f + __expf(-z));
        }
    }
}

// ---------------- main deformable conv: MFMA, 2 K-phases, B from global, fused update_mask ----------------
__global__ __launch_bounds__(256, 4) void deform_main_mfma(
    const short* __restrict__ xt, const float* __restrict__ off_px,
    const float* __restrict__ mask_in, const bf16x8* __restrict__ wd,
    const float* __restrict__ bias,
    float* __restrict__ out, float* __restrict__ upd)
{
    int bid = blockIdx.x;
    int wg = ((bid & 7) << 7) | (bid >> 3);
    int wid = threadIdx.x >> 6, lane = threadIdx.x & 63;
    int r = lane & 15, lg = lane >> 4;
    int g0 = wg * 64 + wid * 16;
    int gp = g0 + r;
    int b = gp >> 14, p = gp & (HWSZ - 1);
    int i = p >> 7, j = p & 127;
    const short* xb = xt + ((size_t)(b << 14)) * XSTR;
    const float* mb = mask_in + (size_t)b * HWSZ;

    // hoisted offset/mask loads: 7 float4 = slots 0..27 (27 used)
    float ov[28];
    {
        const float4* op = (const float4*)(off_px + (size_t)gp * 32);
#pragma unroll
        for (int q = 0; q < 7; ++q) {
            float4 t = op[q];
            ov[4*q+0] = t.x; ov[4*q+1] = t.y; ov[4*q+2] = t.z; ov[4*q+3] = t.w;
        }
    }

    f32x4 acc0 = {0,0,0,0}, acc1 = {0,0,0,0}, acc2 = {0,0,0,0}, acc3 = {0,0,0,0};
    float um = 0.f;

#pragma unroll
    for (int ks = 0; ks < 2; ++ks) {
        int co = ks * 32 + lg * 8;
#pragma unroll
        for (int k = 0; k < KK; ++k) {
            float dy = ov[2*k], dx = ov[2*k+1], m = ov[18+k];
            float py  = dy + (float)(k / 3 + i - 1);
            float pxx = dx + (float)(k % 3 + j - 1);
            float fy = floorf(py), fx = floorf(pxx);
            float wy = py - fy, wx = pxx - fx;
            int y0 = (int)fy, x0 = (int)fx;
            int y1 = y0 + 1, x1 = x0 + 1;
            bool vy0 = (unsigned)y0 < HH, vy1 = (unsigned)y1 < HH;
            bool vx0 = (unsigned)x0 < WW, vx1 = (unsigned)x1 < WW;
            int yc0 = min(max(y0, 0), HH - 1), yc1 = min(max(y1, 0), HH - 1);
            int xc0 = min(max(x0, 0), WW - 1), xc1 = min(max(x1, 0), WW - 1);
            float r00 = (vy0 && vx0) ? (1.f - wy) * (1.f - wx) : 0.f;
            float r01 = (vy0 && vx1) ? (1.f - wy) * wx : 0.f;
            float r10 = (vy1 && vx0) ? wy * (1.f - wx) : 0.f;
            float r11 = (vy1 && vx1) ? wy * wx : 0.f;
            int i00 = yc0 * WW + xc0, i01 = yc0 * WW + xc1;
            int i10 = yc1 * WW + xc0, i11 = yc1 * WW + xc1;

            if (ks == 0)
                um += r00 * mb[i00] + r01 * mb[i01] + r10 * mb[i10] + r11 * mb[i11];

            float w00 = r00 * m, w01 = r01 * m, w10 = r10 * m, w11 = r11 * m;

            U4 c00, c01, c10, c11;
            c00.v = *(const uint4*)(xb + i00 * XSTR + co);
            c01.v = *(const uint4*)(xb + i01 * XSTR + co);
            c10.v = *(const uint4*)(xb + i10 * XSTR + co);
            c11.v = *(const uint4*)(xb + i11 * XSTR + co);
            union { bf16x8 s8; unsigned u[4]; } A;
#pragma unroll
            for (int q = 0; q < 4; ++q) {
                unsigned d00 = c00.a[q], d01 = c01.a[q], d10 = c10.a[q], d11 = c11.a[q];
                float vlo = fmaf(w00, bflo(d00), fmaf(w01, bflo(d01),
                            fmaf(w10, bflo(d10), w11 * bflo(d11))));
                float vhi = fmaf(w00, bfhi(d00), fmaf(w01, bfhi(d01),
                            fmaf(w10, bfhi(d10), w11 * bfhi(d11))));
                A.u[q] = cvtpk(vlo, vhi);
            }
            const bf16x8* wbk = wd + ((ks * 9 + k) * 4) * 64 + lane;
            bf16x8 B0 = wbk[0];
            bf16x8 B1 = wbk[64];
            bf16x8 B2 = wbk[128];
            bf16x8 B3 = wbk[192];
            acc0 = __builtin_amdgcn_mfma_f32_16x16x32_bf16(A.s8, B0, acc0, 0, 0, 0);
            acc1 = __builtin_amdgcn_mfma_f32_16x16x32_bf16(A.s8, B1, acc1, 0, 0, 0);
            acc2 = __builtin_amdgcn_mfma_f32_16x16x32_bf16(A.s8, B2, acc2, 0, 0, 0);
            acc3 = __builtin_amdgcn_mfma_f32_16x16x32_bf16(A.s8, B3, acc3, 0, 0, 0);
        }
    }

    um = fminf(fmaxf(64.f * um, 0.f), 1.f);
    if (lane < 16) upd[g0 + lane] = um;

    int oc = lane & 15;
    int pr0 = lg * 4;
    float u[4];
#pragma unroll
    for (int rr = 0; rr < 4; ++rr) u[rr] = __shfl(um, pr0 + rr, 64);

#define STORE_NT(ACC, NT)                                                     \
    {                                                                         \
        float bo = bias[(NT) * 16 + oc];                                      \
        _Pragma("unroll")                                                     \
        for (int rr = 0; rr < 4; ++rr) {                                      \
            int gg = g0 + pr0 + rr;                                           \
            int bb = gg >> 14;                                                \
            int pp = gg & (HWSZ - 1);                                         \
            out[((size_t)(bb * 64 + (NT) * 16 + oc)) * HWSZ + pp] =           \
                (ACC[rr] + bo) * u[rr];                                       \
        }                                                                     \
    }
    STORE_NT(acc0, 0)
    STORE_NT(acc1, 1)
    STORE_NT(acc2, 2)
    STORE_NT(acc3, 3)
#undef STORE_NT
}

extern "C" void kernel_launch(void* const* d_in, const int* in_sizes, int n_in,
                              void* d_out, int out_size, void* d_ws, size_t ws_size,
                              hipStream_t stream) {
    const float* input    = (const float*)d_in[0];
    const float* mask_in  = (const float*)d_in[1];
    const float* weight   = (const float*)d_in[2];
    const float* bias     = (const float*)d_in[3];
    const float* offset_w = (const float*)d_in[4];
    const float* offset_b = (const float*)d_in[5];
    const float* mask_w   = (const float*)d_in[6];
    const float* mask_b   = (const float*)d_in[7];

    float* out = (float*)d_out;
    float* upd = out + (size_t)NB * 64 * HWSZ;

    float* ws     = (float*)d_ws;
    float* off_px = ws;                                   // 65536*32 f32 = 8.4 MB
    short* wd2    = (short*)(off_px + (size_t)65536*32);  // 36,864 bf16
    short* wc2    = wd2 + 36864;                          // 27,648 bf16
    short* xt     = wc2 + 27648;                          // 65536*96 bf16 = 12.6 MB

    hipLaunchKernelGGL(prep_kernel, dim3(1168), dim3(256), 0, stream,
                       input, mask_in, weight, offset_w, mask_w, xt, wd2, wc2);
    hipLaunchKernelGGL(conv_offset_mfma, dim3(1024), dim3(256), 0, stream,
                       xt, (const bf16x8*)wc2, offset_b, mask_b, off_px);
    hipLaunchKernelGGL(deform_main_mfma, dim3(1024), dim3(256), 0, stream,
                       xt, off_px, mask_in, (const bf16x8*)wd2, bias, out, upd);
}

// Round 8
// 69.295 us; speedup vs baseline: 1.0905x; 1.0905x over previous
//
#include <hip/hip_runtime.h>

#define HH 128
#define WW 128
#define HWSZ (HH*WW)
#define NB 4
#define KK 9
#define XSTR 96   // NHWC channel stride in bf16 elems (192 B): c0-63 input, c64 mask, c65-95 zero

typedef short bf16x8 __attribute__((ext_vector_type(8)));
typedef float f32x4 __attribute__((ext_vector_type(4)));

union U4 { uint4 v; unsigned a[4]; };

__device__ __forceinline__ short f2bf(float f) {
    union { float f; unsigned u; } v; v.f = f;
    unsigned r = v.u + 0x7FFFu + ((v.u >> 16) & 1u);
    return (short)(r >> 16);
}
__device__ __forceinline__ float bflo(unsigned dw) {
    union { unsigned u; float f; } v; v.u = dw << 16; return v.f;
}
__device__ __forceinline__ float bfhi(unsigned dw) {
    union { unsigned u; float f; } v; v.u = dw & 0xFFFF0000u; return v.f;
}
__device__ __forceinline__ unsigned cvtpk(float lo, float hi) {
    unsigned r;
    asm("v_cvt_pk_bf16_f32 %0, %1, %2" : "=v"(r) : "v"(lo), "v"(hi));
    return r;
}

// ---------------- prep: NHWC-bf16 transpose (banded) + weight repack ----------------
// xt : [NB*HWSZ][96] bf16: c0-63 input, c64 = mask_in, c65-95 = 0
// wd2: deform B frags [ks(2)][tap(9)][nt(4)][lane(64)][8] bf16 (36,864)
// wc2: conv   B frags [ks(3)][tap(9)][nt(2)][lane(64)][8] bf16 (27,648); ks=2 = mask channel
__global__ __launch_bounds__(256) void prep_kernel(
    const float* __restrict__ input,
    const float* __restrict__ mask_in,
    const float* __restrict__ weight,
    const float* __restrict__ offset_w,
    const float* __restrict__ mask_w,
    short* __restrict__ xt,
    short* __restrict__ wd2,
    short* __restrict__ wc2)
{
    __shared__ short lds[64 * 104];   // stride 104 shorts = 208 B -> 16B-aligned rows
    int bid = blockIdx.x;
    if (bid < 1024) {
        int wg = ((bid & 7) << 7) | (bid >> 3);   // XCD band swizzle
        int g0 = wg * 64;
        int b  = g0 >> 14;
        int p0 = g0 & (HWSZ - 1);
        int px = threadIdx.x & 63;
        int cq = threadIdx.x >> 6;
#pragma unroll
        for (int it = 0; it < 24; ++it) {
            int c = it * 4 + cq;
            float v;
            if (c < 64)       v = input[((size_t)(b * 64 + c)) * HWSZ + p0 + px];
            else if (c == 64) v = mask_in[(size_t)b * HWSZ + p0 + px];
            else              v = 0.f;
            lds[px * 104 + c] = f2bf(v);
        }
        __syncthreads();
#pragma unroll
        for (int it = 0; it < 3; ++it) {
            int idx = it * 256 + threadIdx.x;
            if (idx < 768) {
                int ppx = idx / 12, s = idx - ppx * 12;
                bf16x8 v = *(const bf16x8*)&lds[ppx * 104 + s * 8];
                *(bf16x8*)&xt[((size_t)(g0 + ppx)) * XSTR + s * 8] = v;
            }
        }
    } else {
        int idx = (bid - 1024) * 256 + threadIdx.x;   // 0..36863
        if (idx < 36864) {
            int j = idx & 7, l = (idx >> 3) & 63, f = idx >> 9;
            int nt = f & 3, t9 = f >> 2;
            int k = t9 % 9, ks = t9 / 9;
            int o = nt * 16 + (l & 15);
            int c = ks * 32 + ((l >> 4) & 3) * 8 + j;
            wd2[idx] = f2bf(weight[(o * 64 + c) * 9 + k]);
        }
        if (idx < 27648) {
            int j = idx & 7, l = (idx >> 3) & 63, f = idx >> 9;
            int nt = f & 1, t9 = f >> 1;
            int k = t9 % 9, ks = t9 / 9;
            int o = nt * 16 + (l & 15);
            int c = ks * 32 + ((l >> 4) & 3) * 8 + j;
            float v = 0.f;
            if (c <= 64) {
                if (o < 18)      v = offset_w[(o * 65 + c) * 9 + k];
                else if (o < 27) v = mask_w[((o - 18) * 65 + c) * 9 + k];
            }
            wc2[idx] = f2bf(v);
        }
    }
}

// ---------------- conv (65ch in, 27ch out, 3x3, pad 1): MFMA, tap-outer, batched A-loads ----------------
// off_px: [NB*HWSZ][32] f32: 0..17 offsets (dy/dx), 18..26 sigmoid(mask)
__global__ __launch_bounds__(256, 4) void conv_offset_mfma(
    const short* __restrict__ xt, const bf16x8* __restrict__ wc,
    const float* __restrict__ offset_b, const float* __restrict__ mask_b,
    float* __restrict__ off_px)
{
    int bid = blockIdx.x;
    int wg = ((bid & 7) << 7) | (bid >> 3);
    int wid = threadIdx.x >> 6, lane = threadIdx.x & 63;
    int r = lane & 15, lg = lane >> 4;
    int g0 = wg * 64 + wid * 16;
    int gp = g0 + r;
    int b = gp >> 14, p = gp & (HWSZ - 1);
    int i = p >> 7, j = p & 127;
    const short* xb = xt + ((size_t)(b << 14)) * XSTR + lg * 8;

    f32x4 acc0 = {0,0,0,0}, acc1 = {0,0,0,0};

#pragma unroll
    for (int t = 0; t < 9; ++t) {
        int yy = i + t / 3 - 1, xx = j + t % 3 - 1;
        bool v = ((unsigned)yy < HH) && ((unsigned)xx < WW);
        int nb = (v ? yy * WW + xx : 0) * XSTR;
        union { bf16x8 s8; uint4 u; } A[3];
#pragma unroll
        for (int ks = 0; ks < 3; ++ks) {
            A[ks].u = *(const uint4*)(xb + nb + ks * 32);
            if (!v) { A[ks].u.x = 0; A[ks].u.y = 0; A[ks].u.z = 0; A[ks].u.w = 0; }
        }
#pragma unroll
        for (int ks = 0; ks < 3; ++ks) {
            const bf16x8* wck = wc + ((ks * 9 + t) * 2) * 64 + lane;
            bf16x8 B0 = wck[0];
            bf16x8 B1 = wck[64];
            acc0 = __builtin_amdgcn_mfma_f32_16x16x32_bf16(A[ks].s8, B0, acc0, 0, 0, 0);
            acc1 = __builtin_amdgcn_mfma_f32_16x16x32_bf16(A[ks].s8, B1, acc1, 0, 0, 0);
        }
    }

    int oc = lane & 15, pr0 = lg * 4;
#pragma unroll
    for (int rr = 0; rr < 4; ++rr) {
        int gpix = g0 + pr0 + rr;
        float* orow = off_px + (size_t)gpix * 32;
        orow[oc] = acc0[rr] + offset_b[oc];
        int oc2 = 16 + oc;
        if (oc2 < 18) {
            orow[oc2] = acc1[rr] + offset_b[oc2];
        } else if (oc2 < 27) {
            float z = acc1[rr] + mask_b[oc2 - 18];
            orow[oc2] = 1.f / (1.f + __expf(-z));
        }
    }
}

// ---------------- main deformable conv: MFMA, tap-outer, 8-gather MLP, fused update_mask ----------------
__global__ __launch_bounds__(256, 4) void deform_main_mfma(
    const short* __restrict__ xt, const float* __restrict__ off_px,
    const float* __restrict__ mask_in, const bf16x8* __restrict__ wd,
    const float* __restrict__ bias,
    float* __restrict__ out, float* __restrict__ upd)
{
    int bid = blockIdx.x;
    int wg = ((bid & 7) << 7) | (bid >> 3);
    int wid = threadIdx.x >> 6, lane = threadIdx.x & 63;
    int r = lane & 15, lg = lane >> 4;
    int g0 = wg * 64 + wid * 16;
    int gp = g0 + r;
    int b = gp >> 14, p = gp & (HWSZ - 1);
    int i = p >> 7, j = p & 127;
    const short* xb = xt + ((size_t)(b << 14)) * XSTR + lg * 8;
    const float* mb = mask_in + (size_t)b * HWSZ;

    // hoisted offset/mask loads: 7 float4 = slots 0..27 (27 used)
    float ov[28];
    {
        const float4* op = (const float4*)(off_px + (size_t)gp * 32);
#pragma unroll
        for (int q = 0; q < 7; ++q) {
            float4 t = op[q];
            ov[4*q+0] = t.x; ov[4*q+1] = t.y; ov[4*q+2] = t.z; ov[4*q+3] = t.w;
        }
    }

    f32x4 acc0 = {0,0,0,0}, acc1 = {0,0,0,0}, acc2 = {0,0,0,0}, acc3 = {0,0,0,0};
    float um = 0.f;

#pragma unroll
    for (int k = 0; k < KK; ++k) {
        float dy = ov[2*k], dx = ov[2*k+1], m = ov[18+k];
        float py  = dy + (float)(k / 3 + i - 1);
        float pxx = dx + (float)(k % 3 + j - 1);
        float fy = floorf(py), fx = floorf(pxx);
        float wy = py - fy, wx = pxx - fx;
        int y0 = (int)fy, x0 = (int)fx;
        int y1 = y0 + 1, x1 = x0 + 1;
        bool vy0 = (unsigned)y0 < HH, vy1 = (unsigned)y1 < HH;
        bool vx0 = (unsigned)x0 < WW, vx1 = (unsigned)x1 < WW;
        int yc0 = min(max(y0, 0), HH - 1), yc1 = min(max(y1, 0), HH - 1);
        int xc0 = min(max(x0, 0), WW - 1), xc1 = min(max(x1, 0), WW - 1);
        float r00 = (vy0 && vx0) ? (1.f - wy) * (1.f - wx) : 0.f;
        float r01 = (vy0 && vx1) ? (1.f - wy) * wx : 0.f;
        float r10 = (vy1 && vx0) ? wy * (1.f - wx) : 0.f;
        float r11 = (vy1 && vx1) ? wy * wx : 0.f;
        int i00 = yc0 * WW + xc0, i01 = yc0 * WW + xc1;
        int i10 = yc1 * WW + xc0, i11 = yc1 * WW + xc1;

        // all 8 gathers issued together (4 corners x 2 channel-halves)
        U4 g00[2], g01[2], g10[2], g11[2];
#pragma unroll
        for (int ks = 0; ks < 2; ++ks) {
            g00[ks].v = *(const uint4*)(xb + i00 * XSTR + ks * 32);
            g01[ks].v = *(const uint4*)(xb + i01 * XSTR + ks * 32);
            g10[ks].v = *(const uint4*)(xb + i10 * XSTR + ks * 32);
            g11[ks].v = *(const uint4*)(xb + i11 * XSTR + ks * 32);
        }

        um += r00 * mb[i00] + r01 * mb[i01] + r10 * mb[i10] + r11 * mb[i11];

        float w00 = r00 * m, w01 = r01 * m, w10 = r10 * m, w11 = r11 * m;

#pragma unroll
        for (int ks = 0; ks < 2; ++ks) {
            union { bf16x8 s8; unsigned u[4]; } A;
#pragma unroll
            for (int q = 0; q < 4; ++q) {
                unsigned d00 = g00[ks].a[q], d01 = g01[ks].a[q];
                unsigned d10 = g10[ks].a[q], d11 = g11[ks].a[q];
                float vlo = fmaf(w00, bflo(d00), fmaf(w01, bflo(d01),
                            fmaf(w10, bflo(d10), w11 * bflo(d11))));
                float vhi = fmaf(w00, bfhi(d00), fmaf(w01, bfhi(d01),
                            fmaf(w10, bfhi(d10), w11 * bfhi(d11))));
                A.u[q] = cvtpk(vlo, vhi);
            }
            const bf16x8* wbk = wd + ((ks * 9 + k) * 4) * 64 + lane;
            bf16x8 B0 = wbk[0];
            bf16x8 B1 = wbk[64];
            bf16x8 B2 = wbk[128];
            bf16x8 B3 = wbk[192];
            acc0 = __builtin_amdgcn_mfma_f32_16x16x32_bf16(A.s8, B0, acc0, 0, 0, 0);
            acc1 = __builtin_amdgcn_mfma_f32_16x16x32_bf16(A.s8, B1, acc1, 0, 0, 0);
            acc2 = __builtin_amdgcn_mfma_f32_16x16x32_bf16(A.s8, B2, acc2, 0, 0, 0);
            acc3 = __builtin_amdgcn_mfma_f32_16x16x32_bf16(A.s8, B3, acc3, 0, 0, 0);
        }
    }

    um = fminf(fmaxf(64.f * um, 0.f), 1.f);
    if (lane < 16) upd[g0 + lane] = um;

    int oc = lane & 15;
    int pr0 = lg * 4;
    float u[4];
#pragma unroll
    for (int rr = 0; rr < 4; ++rr) u[rr] = __shfl(um, pr0 + rr, 64);

#define STORE_NT(ACC, NT)                                                     \
    {                                                                         \
        float bo = bias[(NT) * 16 + oc];                                      \
        _Pragma("unroll")                                                     \
        for (int rr = 0; rr < 4; ++rr) {                                      \
            int gg = g0 + pr0 + rr;                                           \
            int bb = gg >> 14;                                                \
            int pp = gg & (HWSZ - 1);                                         \
            out[((size_t)(bb * 64 + (NT) * 16 + oc)) * HWSZ + pp] =           \
                (ACC[rr] + bo) * u[rr];                                       \
        }                                                                     \
    }
    STORE_NT(acc0, 0)
    STORE_NT(acc1, 1)
    STORE_NT(acc2, 2)
    STORE_NT(acc3, 3)
#undef STORE_NT
}

extern "C" void kernel_launch(void* const* d_in, const int* in_sizes, int n_in,
                              void* d_out, int out_size, void* d_ws, size_t ws_size,
                              hipStream_t stream) {
    const float* input    = (const float*)d_in[0];
    const float* mask_in  = (const float*)d_in[1];
    const float* weight   = (const float*)d_in[2];
    const float* bias     = (const float*)d_in[3];
    const float* offset_w = (const float*)d_in[4];
    const float* offset_b = (const float*)d_in[5];
    const float* mask_w   = (const float*)d_in[6];
    const float* mask_b   = (const float*)d_in[7];

    float* out = (float*)d_out;
    float* upd = out + (size_t)NB * 64 * HWSZ;

    float* ws     = (float*)d_ws;
    float* off_px = ws;                                   // 65536*32 f32 = 8.4 MB
    short* wd2    = (short*)(off_px + (size_t)65536*32);  // 36,864 bf16
    short* wc2    = wd2 + 36864;                          // 27,648 bf16
    short* xt     = wc2 + 27648;                          // 65536*96 bf16 = 12.6 MB

    hipLaunchKernelGGL(prep_kernel, dim3(1168), dim3(256), 0, stream,
                       input, mask_in, weight, offset_w, mask_w, xt, wd2, wc2);
    hipLaunchKernelGGL(conv_offset_mfma, dim3(1024), dim3(256), 0, stream,
                       xt, (const bf16x8*)wc2, offset_b, mask_b, off_px);
    hipLaunchKernelGGL(deform_main_mfma, dim3(1024), dim3(256), 0, stream,
                       xt, off_px, mask_in, (const bf16x8*)wd2, bias, out, upd);
}